// Round 1
// baseline (466.944 us; speedup 1.0000x reference)
//
#include <hip/hip_runtime.h>
#include <stdint.h>

typedef __attribute__((ext_vector_type(8))) short bhalf8;
typedef __attribute__((ext_vector_type(4))) float fx4;

__device__ __forceinline__ unsigned short f2bf(float f) {
    unsigned u = __builtin_bit_cast(unsigned, f);
    unsigned r = (u + 0x7fffu + ((u >> 16) & 1u)) >> 16;
    return (unsigned short)r;
}
__device__ __forceinline__ float bf2f(unsigned short h) {
    unsigned u = ((unsigned)h) << 16;
    return __builtin_bit_cast(float, u);
}
__device__ __forceinline__ float lrelu(float v) { return v > 0.f ? v : 0.2f * v; }

typedef __attribute__((address_space(1))) void as1_void;
typedef __attribute__((address_space(3))) void as3_void;
__device__ __forceinline__ void gl_lds16(const void* g, void* l) {
    __builtin_amdgcn_global_load_lds((as1_void*)(void*)g, (as3_void*)l, 16, 0, 0);
}

// ---------------- styles: s = w @ a^T + b ----------------
__global__ __launch_bounds__(256) void style_kernel(
    const float* __restrict__ w,
    const float* __restrict__ a1w, const float* __restrict__ a1b,
    const float* __restrict__ a2w, const float* __restrict__ a2b,
    const float* __restrict__ a3w, const float* __restrict__ a3b,
    float* __restrict__ s1, float* __restrict__ s2, float* __restrict__ s3)
{
    __shared__ float wv[512];
    int b = blockIdx.x, t = threadIdx.x;
    wv[t] = w[b * 512 + t];
    wv[t + 256] = w[b * 512 + t + 256];
    __syncthreads();
    #pragma unroll
    for (int rep = 0; rep < 2; ++rep) {
        int i = t + rep * 256;
        const float* row = a1w + (size_t)i * 512;
        float acc = 0.f;
        for (int d = 0; d < 512; ++d) acc += wv[d] * row[d];
        s1[b * 512 + i] = acc + a1b[i];
    }
    {
        const float* row = a2w + (size_t)t * 512;
        float acc = 0.f;
        for (int d = 0; d < 512; ++d) acc += wv[d] * row[d];
        s2[b * 256 + t] = acc + a2b[t];
    }
    {
        const float* row = a3w + (size_t)t * 512;
        float acc = 0.f;
        for (int d = 0; d < 512; ++d) acc += wv[d] * row[d];
        s3[b * 256 + t] = acc + a3b[t];
    }
}

// ---------------- demod: d[b,o] = rsqrt(sum_{i,tap}(w*s)^2 + eps) ----------------
__global__ __launch_bounds__(256) void demod_kernel(
    const float* __restrict__ w1, const float* __restrict__ w2,
    const float* __restrict__ s1, const float* __restrict__ s2,
    float* __restrict__ d1, float* __restrict__ d2)
{
    int blk = blockIdx.x;                 // 2048 blocks
    int conv = blk >> 10, b = (blk >> 8) & 3, o = blk & 255;
    int t = threadIdx.x;
    int cin = conv ? 256 : 512;
    const float* s = conv ? (s2 + b * 256) : (s1 + b * 512);
    const float* row = (conv ? w2 : w1) + (size_t)o * cin * 9;
    __shared__ float sv[512];
    for (int i = t; i < cin; i += 256) { float v = s[i]; sv[i] = v * v; }
    __syncthreads();
    float sum = 0.f;
    int n = cin * 9;
    for (int k = t; k < n; k += 256) {
        float v = row[k];
        sum += v * v * sv[k / 9];
    }
    #pragma unroll
    for (int off = 32; off; off >>= 1) sum += __shfl_down(sum, off, 64);
    __shared__ float red[4];
    if ((t & 63) == 0) red[t >> 6] = sum;
    __syncthreads();
    if (t == 0) {
        float tot = red[0] + red[1] + red[2] + red[3];
        (conv ? d2 : d1)[b * 256 + o] = rsqrtf(tot + 1e-8f);
    }
}

// ---------------- pack weights to bf16, fragment-linear layout ----------------
// layout: [mblk][dy][ic][dx][kh][m(128)][e(8)]
__global__ __launch_bounds__(256) void pack_kernel(
    const float* __restrict__ w1, const float* __restrict__ w2,
    unsigned short* __restrict__ wp1, unsigned short* __restrict__ wp2)
{
    int tid = blockIdx.x * 256 + threadIdx.x;
    const int N1 = 1179648, N2 = 589824;
    if (tid < N1) {
        int e = tid & 7, m = (tid >> 3) & 127, kh = (tid >> 10) & 3;
        int dx = (tid >> 12) % 3, ic = (tid / 12288) & 15;
        int dy = (tid / 196608) % 3, mblk = tid / 589824;
        int o = mblk * 128 + m, ci = ic * 32 + kh * 8 + e;
        wp1[tid] = f2bf(w1[((size_t)o * 512 + ci) * 9 + dy * 3 + dx]);
    } else if (tid < N1 + N2) {
        int t2 = tid - N1;
        int e = t2 & 7, m = (t2 >> 3) & 127, kh = (t2 >> 10) & 3;
        int dx = (t2 >> 12) % 3, ic = (t2 / 12288) & 7;
        int dy = (t2 / 98304) % 3, mblk = t2 / 294912;
        int o = mblk * 128 + m, ci = ic * 32 + kh * 8 + e;
        wp2[t2] = f2bf(w2[((size_t)o * 256 + ci) * 9 + dy * 3 + dx]);
    }
}

// ---------------- bilinear 2x upsample + s1 modulate -> bf16 channels-last ----------------
__global__ __launch_bounds__(256) void upsample_kernel(
    const float* __restrict__ x, const float* __restrict__ s1,
    unsigned short* __restrict__ xu)   // [4][128][128][512]
{
    __shared__ float L[2][64][65];
    int bid = blockIdx.x, t = threadIdx.x;
    int yo = bid & 127, b = bid >> 7;
    int k = yo >> 1;
    int sy0, sy1; float wy0, wy1;
    if ((yo & 1) == 0) { sy0 = k > 0 ? k - 1 : 0; sy1 = k; wy0 = 0.25f; wy1 = 0.75f; }
    else               { sy0 = k; sy1 = k < 63 ? k + 1 : 63; wy0 = 0.75f; wy1 = 0.25f; }
    for (int c0 = 0; c0 < 512; c0 += 64) {
        __syncthreads();
        #pragma unroll
        for (int j = 0; j < 32; ++j) {      // stage 2 rows x 64 c x 64 px
            int f = t + j * 256;
            int idx = f & 63, rowid = f >> 6;
            int cc = rowid & 63, which = rowid >> 6;
            int sy = which ? sy1 : sy0;
            L[which][cc][idx] = x[((size_t)(b * 512 + c0 + cc) * 64 + sy) * 64 + idx];
        }
        __syncthreads();
        #pragma unroll
        for (int j = 0; j < 16; ++j) {      // 128 x * 32 cpairs
            int it = t + j * 256;
            int cp = it & 31, xo = it >> 5;
            int kk = xo >> 1, sx0, sx1; float wx0, wx1;
            if ((xo & 1) == 0) { sx0 = kk > 0 ? kk - 1 : 0; sx1 = kk; wx0 = 0.25f; wx1 = 0.75f; }
            else               { sx0 = kk; sx1 = kk < 63 ? kk + 1 : 63; wx0 = 0.75f; wx1 = 0.25f; }
            int c = cp * 2;
            float A0 = wx0 * L[0][c][sx0] + wx1 * L[0][c][sx1];
            float B0 = wx0 * L[1][c][sx0] + wx1 * L[1][c][sx1];
            float A1 = wx0 * L[0][c + 1][sx0] + wx1 * L[0][c + 1][sx1];
            float B1 = wx0 * L[1][c + 1][sx0] + wx1 * L[1][c + 1][sx1];
            float v0 = (wy0 * A0 + wy1 * B0) * s1[b * 512 + c0 + c];
            float v1 = (wy0 * A1 + wy1 * B1) * s1[b * 512 + c0 + c + 1];
            unsigned pk = (unsigned)f2bf(v0) | ((unsigned)f2bf(v1) << 16);
            *(unsigned*)&xu[((size_t)(b * 128 + yo) * 128 + xo) * 512 + c0 + c] = pk;
        }
    }
}

// ---------------- 3x3 conv, implicit im2col, bf16 MFMA 16x16x32 ----------------
// inp channels-last [4][128][128][CIN] (already style-modulated)
// out: outmod = bf16( lrelu(acc*d + bias) * post ), channels-last
//      (IS_CONV2) outf = f32 lrelu(acc*d + bias), NCHW
template<int CIN, bool IS_CONV2>
__global__ __launch_bounds__(256) void conv3x3_kernel(
    const unsigned short* __restrict__ inp,
    const unsigned short* __restrict__ wpack,
    const float* __restrict__ dvec,
    const float* __restrict__ bias,
    const float* __restrict__ post,
    unsigned short* __restrict__ outmod,
    float* __restrict__ outf)
{
    constexpr int NIC = CIN / 32;
    __shared__ __attribute__((aligned(16))) short Alds[3 * 4096];  // [dx][kh][m128][e8]
    __shared__ __attribute__((aligned(16))) short Blds[130 * 32];  // [slot130][i8x8 swizzled]
    const int tid = threadIdx.x;
    const int lane = tid & 63;
    const int wvi = tid >> 6;
    const int bid = blockIdx.x;
    const int y = bid & 127;
    const int mblk = (bid >> 7) & 1;
    const int b = bid >> 8;
    const int wm = (wvi >> 1) * 64;
    const int wn = (wvi & 1) * 64;
    const int lhi = lane >> 4;
    const int llo = lane & 15;

    if (tid < 8) {   // zero column-halo pad slots 0 and 129
        int s = (tid >= 4) ? 129 : 0;
        *(int4*)((char*)Blds + s * 64 + (tid & 3) * 16) = make_int4(0, 0, 0, 0);
    }

    fx4 acc[4][4];
    #pragma unroll
    for (int mt = 0; mt < 4; ++mt)
        #pragma unroll
        for (int nt = 0; nt < 4; ++nt) acc[mt][nt] = (fx4){0.f, 0.f, 0.f, 0.f};

    for (int dy = 0; dy < 3; ++dy) {
        const int yy = y + dy - 1;
        const bool inrow = ((unsigned)yy < 128u);
        const unsigned short* brow = inp + ((size_t)(b * 128 + yy) * 128) * CIN;
        for (int ic = 0; ic < NIC; ++ic) {
            __syncthreads();
            const unsigned short* asrc = wpack + ((size_t)((mblk * 3 + dy) * NIC + ic)) * (3 * 4096);
            #pragma unroll
            for (int j = 0; j < 6; ++j) {          // A: 24 KB linear
                int g = tid + j * 256;
                gl_lds16(asrc + (size_t)g * 8, (char*)Alds + g * 16);
            }
            if (inrow) {
                #pragma unroll
                for (int j = 0; j < 2; ++j) {      // B: 8 KB, swizzled gather
                    int g = tid + j * 256;
                    int xg = g >> 2, i8 = g & 3;
                    int i8s = i8 ^ ((xg >> 1) & 3);
                    gl_lds16(brow + (size_t)xg * CIN + ic * 32 + i8s * 8,
                             (char*)Blds + 64 + g * 16);
                }
            } else {
                #pragma unroll
                for (int j = 0; j < 2; ++j) {
                    int g = tid + j * 256;
                    *(int4*)((char*)Blds + 64 + g * 16) = make_int4(0, 0, 0, 0);
                }
            }
            __syncthreads();
            #pragma unroll
            for (int dx = 0; dx < 3; ++dx) {
                bhalf8 af[4], bfr[4];
                #pragma unroll
                for (int mt = 0; mt < 4; ++mt)
                    af[mt] = *(const bhalf8*)&Alds[dx * 4096 + (lhi * 128 + wm + mt * 16 + llo) * 8];
                #pragma unroll
                for (int nt = 0; nt < 4; ++nt) {
                    int s = wn + nt * 16 + llo + dx;
                    int key = ((s - 1) >> 1) & 3;
                    bfr[nt] = *(const bhalf8*)&Blds[s * 32 + ((lhi ^ key) << 3)];
                }
                #pragma unroll
                for (int mt = 0; mt < 4; ++mt)
                    #pragma unroll
                    for (int nt = 0; nt < 4; ++nt)
                        acc[mt][nt] = __builtin_amdgcn_mfma_f32_16x16x32_bf16(
                            af[mt], bfr[nt], acc[mt][nt], 0, 0, 0);
            }
        }
    }

    // epilogue
    #pragma unroll
    for (int mt = 0; mt < 4; ++mt) {
        const int o0 = mblk * 128 + wm + mt * 16 + lhi * 4;
        const fx4 d4 = *(const fx4*)(dvec + b * 256 + o0);
        const fx4 bb4 = *(const fx4*)(bias + o0);
        const fx4 p4 = *(const fx4*)(post + b * 256 + o0);
        #pragma unroll
        for (int nt = 0; nt < 4; ++nt) {
            const int xo = wn + nt * 16 + llo;
            unsigned lo = 0, hi = 0;
            #pragma unroll
            for (int r = 0; r < 4; ++r) {
                float v = acc[mt][nt][r] * d4[r] + bb4[r];
                v = lrelu(v);
                if (IS_CONV2)
                    outf[(((size_t)b * 256 + o0 + r) * 128 + y) * 128 + xo] = v;
                unsigned short ub = f2bf(v * p4[r]);
                if (r < 2) lo |= (unsigned)ub << (16 * r);
                else       hi |= (unsigned)ub << (16 * (r - 2));
            }
            *(uint2*)&outmod[((size_t)(b * 128 + y) * 128 + xo) * 256 + o0] = make_uint2(lo, hi);
        }
    }
}

// ---------------- 1x1 to_rgb on h*s3 (bf16), no demod ----------------
__global__ __launch_bounds__(256) void rgb_kernel(
    const unsigned short* __restrict__ hs3,
    const float* __restrict__ w3, const float* __restrict__ b3,
    float* __restrict__ out)   // d_out + 16777216, [4][3][128][128]
{
    __shared__ float wl[768];
    int t = threadIdx.x;
    for (int i = t; i < 768; i += 256) wl[i] = w3[i];
    __syncthreads();
    int blk = blockIdx.x;                 // 256 blocks
    int b = blk >> 6;
    int y = ((blk & 63) << 1) | (t >> 7);
    int xo = t & 127;
    const unsigned short* src = hs3 + ((size_t)(b * 128 + y) * 128 + xo) * 256;
    float a0 = 0.f, a1 = 0.f, a2 = 0.f;
    for (int c = 0; c < 256; c += 8) {
        int4 pk = *(const int4*)(src + c);
        #pragma unroll
        for (int q = 0; q < 4; ++q) {
            unsigned uu = ((const unsigned*)&pk)[q];
            float ve = bf2f((unsigned short)(uu & 0xffffu));
            float vo = bf2f((unsigned short)(uu >> 16));
            int c2 = c + q * 2;
            a0 += ve * wl[c2] + vo * wl[c2 + 1];
            a1 += ve * wl[256 + c2] + vo * wl[256 + c2 + 1];
            a2 += ve * wl[512 + c2] + vo * wl[512 + c2 + 1];
        }
    }
    size_t base = ((size_t)b * 3 * 128 + y) * 128 + xo;
    out[base]              = lrelu(a0 + b3[0]);
    out[base + 16384]      = lrelu(a1 + b3[1]);
    out[base + 32768]      = lrelu(a2 + b3[2]);
}

extern "C" void kernel_launch(void* const* d_in, const int* in_sizes, int n_in,
                              void* d_out, int out_size, void* d_ws, size_t ws_size,
                              hipStream_t stream) {
    const float* x   = (const float*)d_in[0];
    const float* w   = (const float*)d_in[1];
    const float* w1  = (const float*)d_in[2];
    const float* b1  = (const float*)d_in[3];
    const float* a1w = (const float*)d_in[4];
    const float* a1b = (const float*)d_in[5];
    const float* w2  = (const float*)d_in[6];
    const float* b2  = (const float*)d_in[7];
    const float* a2w = (const float*)d_in[8];
    const float* a2b = (const float*)d_in[9];
    const float* w3  = (const float*)d_in[10];
    const float* b3  = (const float*)d_in[11];
    const float* a3w = (const float*)d_in[12];
    const float* a3b = (const float*)d_in[13];

    char* ws = (char*)d_ws;
    unsigned short* xu  = (unsigned short*)(ws);                 // 67108864 B [4][128][128][512] bf16
    unsigned short* hs3 = (unsigned short*)(ws);                 // aliases xu (xu dead after conv1)
    unsigned short* t1  = (unsigned short*)(ws + 67108864);      // 33554432 B [4][128][128][256] bf16
    unsigned short* wp1 = (unsigned short*)(ws + 100663296);     // 2359296 B
    unsigned short* wp2 = (unsigned short*)(ws + 103022592);     // 1179648 B
    float* s1 = (float*)(ws + 104202240);                        // 4*512
    float* s2 = (float*)(ws + 104210432);                        // 4*256
    float* s3 = (float*)(ws + 104214528);                        // 4*256
    float* d1 = (float*)(ws + 104218624);                        // 4*256
    float* d2 = (float*)(ws + 104222720);                        // 4*256

    float* h_out   = (float*)d_out;
    float* rgb_out = h_out + 16777216;

    style_kernel<<<4, 256, 0, stream>>>(w, a1w, a1b, a2w, a2b, a3w, a3b, s1, s2, s3);
    demod_kernel<<<2048, 256, 0, stream>>>(w1, w2, s1, s2, d1, d2);
    pack_kernel<<<6912, 256, 0, stream>>>(w1, w2, wp1, wp2);
    upsample_kernel<<<512, 256, 0, stream>>>(x, s1, xu);
    conv3x3_kernel<512, false><<<1024, 256, 0, stream>>>(xu, wp1, d1, b1, s2, t1, nullptr);
    conv3x3_kernel<256, true><<<1024, 256, 0, stream>>>(t1, wp2, d2, b2, s3, hs3, h_out);
    rgb_kernel<<<256, 256, 0, stream>>>(hs3, w3, b3, rgb_out);
}

// Round 3
// 391.704 us; speedup vs baseline: 1.1921x; 1.1921x over previous
//
#include <hip/hip_runtime.h>
#include <stdint.h>

typedef __attribute__((ext_vector_type(8))) short bhalf8;
typedef __attribute__((ext_vector_type(4))) float fx4;

__device__ __forceinline__ unsigned short f2bf(float f) {
    unsigned u = __builtin_bit_cast(unsigned, f);
    unsigned r = (u + 0x7fffu + ((u >> 16) & 1u)) >> 16;
    return (unsigned short)r;
}
__device__ __forceinline__ float bf2f(unsigned short h) {
    unsigned u = ((unsigned)h) << 16;
    return __builtin_bit_cast(float, u);
}
__device__ __forceinline__ float lrelu(float v) { return v > 0.f ? v : 0.2f * v; }

typedef __attribute__((address_space(1))) void as1_void;
typedef __attribute__((address_space(3))) void as3_void;
__device__ __forceinline__ void gl_lds16(const void* g, void* l) {
    __builtin_amdgcn_global_load_lds((as1_void*)(void*)g, (as3_void*)l, 16, 0, 0);
}

// ---------------- styles: s = w @ a^T + b  (one wave per output) ----------------
__global__ __launch_bounds__(256) void style_kernel(
    const float* __restrict__ w,
    const float* __restrict__ a1w, const float* __restrict__ a1b,
    const float* __restrict__ a2w, const float* __restrict__ a2b,
    const float* __restrict__ a3w, const float* __restrict__ a3b,
    float* __restrict__ s1, float* __restrict__ s2, float* __restrict__ s3)
{
    int gw = blockIdx.x * 4 + (threadIdx.x >> 6);   // 0..4095
    int lane = threadIdx.x & 63;
    int b = gw >> 10, r = gw & 1023;
    const float* arow; const float* abias; float* dst;
    if (r < 512)      { arow = a1w + (size_t)r * 512;        abias = a1b + r;       dst = s1 + b * 512 + r; }
    else if (r < 768) { int rr = r - 512; arow = a2w + (size_t)rr * 512; abias = a2b + rr; dst = s2 + b * 256 + rr; }
    else              { int rr = r - 768; arow = a3w + (size_t)rr * 512; abias = a3b + rr; dst = s3 + b * 256 + rr; }
    const float* wrow = w + b * 512;
    float acc = 0.f;
    #pragma unroll
    for (int j = 0; j < 8; ++j) {
        int c = lane + j * 64;
        acc += wrow[c] * arow[c];
    }
    #pragma unroll
    for (int off = 32; off; off >>= 1) acc += __shfl_down(acc, off, 64);
    if (lane == 0) *dst = acc + *abias;
}

// ---------------- demod: d[b,o] = rsqrt(sum_{i,tap}(w*s)^2 + eps) ----------------
__global__ __launch_bounds__(256) void demod_kernel(
    const float* __restrict__ w1, const float* __restrict__ w2,
    const float* __restrict__ s1, const float* __restrict__ s2,
    float* __restrict__ d1, float* __restrict__ d2)
{
    int blk = blockIdx.x;                 // 2048 blocks
    int conv = blk >> 10, b = (blk >> 8) & 3, o = blk & 255;
    int t = threadIdx.x;
    int cin = conv ? 256 : 512;
    const float* s = conv ? (s2 + b * 256) : (s1 + b * 512);
    const float* row = (conv ? w2 : w1) + (size_t)o * cin * 9;
    __shared__ float sv[512];
    for (int i = t; i < cin; i += 256) { float v = s[i]; sv[i] = v * v; }
    __syncthreads();
    float sum = 0.f;
    int n = cin * 9;
    for (int k = t; k < n; k += 256) {
        float v = row[k];
        sum += v * v * sv[k / 9];
    }
    #pragma unroll
    for (int off = 32; off; off >>= 1) sum += __shfl_down(sum, off, 64);
    __shared__ float red[4];
    if ((t & 63) == 0) red[t >> 6] = sum;
    __syncthreads();
    if (t == 0) {
        float tot = red[0] + red[1] + red[2] + red[3];
        (conv ? d2 : d1)[b * 256 + o] = rsqrtf(tot + 1e-8f);
    }
}

// ---------------- pack weights to bf16, fragment-linear layout ----------------
// layout: [mblk][dy][ic][dx][kh][m(128)][e(8)]
__global__ __launch_bounds__(256) void pack_kernel(
    const float* __restrict__ w1, const float* __restrict__ w2,
    unsigned short* __restrict__ wp1, unsigned short* __restrict__ wp2)
{
    int tid = blockIdx.x * 256 + threadIdx.x;
    const int N1 = 1179648, N2 = 589824;
    if (tid < N1) {
        int e = tid & 7, m = (tid >> 3) & 127, kh = (tid >> 10) & 3;
        int dx = (tid >> 12) % 3, ic = (tid / 12288) & 15;
        int dy = (tid / 196608) % 3, mblk = tid / 589824;
        int o = mblk * 128 + m, ci = ic * 32 + kh * 8 + e;
        wp1[tid] = f2bf(w1[((size_t)o * 512 + ci) * 9 + dy * 3 + dx]);
    } else if (tid < N1 + N2) {
        int t2 = tid - N1;
        int e = t2 & 7, m = (t2 >> 3) & 127, kh = (t2 >> 10) & 3;
        int dx = (t2 >> 12) % 3, ic = (t2 / 12288) & 7;
        int dy = (t2 / 98304) % 3, mblk = t2 / 294912;
        int o = mblk * 128 + m, ci = ic * 32 + kh * 8 + e;
        wp2[t2] = f2bf(w2[((size_t)o * 256 + ci) * 9 + dy * 3 + dx]);
    }
}

// ---------------- bilinear 2x upsample + s1 modulate -> bf16 channels-last ----------------
__global__ __launch_bounds__(256) void upsample_kernel(
    const float* __restrict__ x, const float* __restrict__ s1,
    unsigned short* __restrict__ xu)   // [4][128][128][512]
{
    __shared__ float L[2][64][65];
    int bid = blockIdx.x, t = threadIdx.x;
    int yo = bid & 127, b = bid >> 7;
    int k = yo >> 1;
    int sy0, sy1; float wy0, wy1;
    if ((yo & 1) == 0) { sy0 = k > 0 ? k - 1 : 0; sy1 = k; wy0 = 0.25f; wy1 = 0.75f; }
    else               { sy0 = k; sy1 = k < 63 ? k + 1 : 63; wy0 = 0.75f; wy1 = 0.25f; }
    for (int c0 = 0; c0 < 512; c0 += 64) {
        __syncthreads();
        #pragma unroll
        for (int j = 0; j < 32; ++j) {      // stage 2 rows x 64 c x 64 px
            int f = t + j * 256;
            int idx = f & 63, rowid = f >> 6;
            int cc = rowid & 63, which = rowid >> 6;
            int sy = which ? sy1 : sy0;
            L[which][cc][idx] = x[((size_t)(b * 512 + c0 + cc) * 64 + sy) * 64 + idx];
        }
        __syncthreads();
        #pragma unroll
        for (int j = 0; j < 16; ++j) {      // 128 x * 32 cpairs
            int it = t + j * 256;
            int cp = it & 31, xo = it >> 5;
            int kk = xo >> 1, sx0, sx1; float wx0, wx1;
            if ((xo & 1) == 0) { sx0 = kk > 0 ? kk - 1 : 0; sx1 = kk; wx0 = 0.25f; wx1 = 0.75f; }
            else               { sx0 = kk; sx1 = kk < 63 ? kk + 1 : 63; wx0 = 0.75f; wx1 = 0.25f; }
            int c = cp * 2;
            float A0 = wx0 * L[0][c][sx0] + wx1 * L[0][c][sx1];
            float B0 = wx0 * L[1][c][sx0] + wx1 * L[1][c][sx1];
            float A1 = wx0 * L[0][c + 1][sx0] + wx1 * L[0][c + 1][sx1];
            float B1 = wx0 * L[1][c + 1][sx0] + wx1 * L[1][c + 1][sx1];
            float v0 = (wy0 * A0 + wy1 * B0) * s1[b * 512 + c0 + c];
            float v1 = (wy0 * A1 + wy1 * B1) * s1[b * 512 + c0 + c + 1];
            unsigned pk = (unsigned)f2bf(v0) | ((unsigned)f2bf(v1) << 16);
            *(unsigned*)&xu[((size_t)(b * 128 + yo) * 128 + xo) * 512 + c0 + c] = pk;
        }
    }
}

// ---------------- 3x3 conv, implicit im2col, bf16 MFMA 16x16x32 ----------------
template<int CIN, bool IS_CONV2>
__global__ __launch_bounds__(256) void conv3x3_kernel(
    const unsigned short* __restrict__ inp,
    const unsigned short* __restrict__ wpack,
    const float* __restrict__ dvec,
    const float* __restrict__ bias,
    const float* __restrict__ post,
    unsigned short* __restrict__ outmod,
    float* __restrict__ outf)
{
    constexpr int NIC = CIN / 32;
    __shared__ __attribute__((aligned(16))) short Alds[3 * 4096];  // [dx][kh][m128][e8]
    __shared__ __attribute__((aligned(16))) short Blds[130 * 32];  // [slot130][i8x8 swizzled]
    const int tid = threadIdx.x;
    const int lane = tid & 63;
    const int wvi = tid >> 6;
    const int bid = blockIdx.x;
    const int y = bid & 127;
    const int mblk = (bid >> 7) & 1;
    const int b = bid >> 8;
    const int wm = (wvi >> 1) * 64;
    const int wn = (wvi & 1) * 64;
    const int lhi = lane >> 4;
    const int llo = lane & 15;

    if (tid < 8) {   // zero column-halo pad slots 0 and 129
        int s = (tid >= 4) ? 129 : 0;
        *(int4*)((char*)Blds + s * 64 + (tid & 3) * 16) = make_int4(0, 0, 0, 0);
    }

    fx4 acc[4][4];
    #pragma unroll
    for (int mt = 0; mt < 4; ++mt)
        #pragma unroll
        for (int nt = 0; nt < 4; ++nt) acc[mt][nt] = (fx4){0.f, 0.f, 0.f, 0.f};

    for (int dy = 0; dy < 3; ++dy) {
        const int yy = y + dy - 1;
        const bool inrow = ((unsigned)yy < 128u);
        const unsigned short* brow = inp + ((size_t)(b * 128 + yy) * 128) * CIN;
        for (int ic = 0; ic < NIC; ++ic) {
            __syncthreads();
            const unsigned short* asrc = wpack + ((size_t)((mblk * 3 + dy) * NIC + ic)) * (3 * 4096);
            #pragma unroll
            for (int j = 0; j < 6; ++j) {          // A: 24 KB linear
                int g = tid + j * 256;
                gl_lds16(asrc + (size_t)g * 8, (char*)Alds + g * 16);
            }
            if (inrow) {
                #pragma unroll
                for (int j = 0; j < 2; ++j) {      // B: 8 KB, swizzled gather
                    int g = tid + j * 256;
                    int xg = g >> 2, i8 = g & 3;
                    int i8s = i8 ^ ((xg >> 1) & 3);
                    gl_lds16(brow + (size_t)xg * CIN + ic * 32 + i8s * 8,
                             (char*)Blds + 64 + g * 16);
                }
            } else {
                #pragma unroll
                for (int j = 0; j < 2; ++j) {
                    int g = tid + j * 256;
                    *(int4*)((char*)Blds + 64 + g * 16) = make_int4(0, 0, 0, 0);
                }
            }
            __syncthreads();
            #pragma unroll
            for (int dx = 0; dx < 3; ++dx) {
                bhalf8 af[4], bfr[4];
                #pragma unroll
                for (int mt = 0; mt < 4; ++mt)
                    af[mt] = *(const bhalf8*)&Alds[dx * 4096 + (lhi * 128 + wm + mt * 16 + llo) * 8];
                #pragma unroll
                for (int nt = 0; nt < 4; ++nt) {
                    int s = wn + nt * 16 + llo + dx;
                    int key = ((s - 1) >> 1) & 3;
                    bfr[nt] = *(const bhalf8*)&Blds[s * 32 + ((lhi ^ key) << 3)];
                }
                #pragma unroll
                for (int mt = 0; mt < 4; ++mt)
                    #pragma unroll
                    for (int nt = 0; nt < 4; ++nt)
                        acc[mt][nt] = __builtin_amdgcn_mfma_f32_16x16x32_bf16(
                            af[mt], bfr[nt], acc[mt][nt], 0, 0, 0);
            }
        }
    }

    // epilogue
    #pragma unroll
    for (int mt = 0; mt < 4; ++mt) {
        const int o0 = mblk * 128 + wm + mt * 16 + lhi * 4;
        const fx4 d4 = *(const fx4*)(dvec + b * 256 + o0);
        const fx4 bb4 = *(const fx4*)(bias + o0);
        const fx4 p4 = *(const fx4*)(post + b * 256 + o0);
        #pragma unroll
        for (int nt = 0; nt < 4; ++nt) {
            const int xo = wn + nt * 16 + llo;
            unsigned lo = 0, hi = 0;
            #pragma unroll
            for (int r = 0; r < 4; ++r) {
                float v = acc[mt][nt][r] * d4[r] + bb4[r];
                v = lrelu(v);
                if (IS_CONV2)
                    outf[(((size_t)b * 256 + o0 + r) * 128 + y) * 128 + xo] = v;
                unsigned short ub = f2bf(v * p4[r]);
                if (r < 2) lo |= (unsigned)ub << (16 * r);
                else       hi |= (unsigned)ub << (16 * (r - 2));
            }
            *(uint2*)&outmod[((size_t)(b * 128 + y) * 128 + xo) * 256 + o0] = make_uint2(lo, hi);
        }
    }
}

// ---------------- 1x1 to_rgb on h*s3 (bf16), coalesced: 4 lanes per pixel ----------------
__global__ __launch_bounds__(256) void rgb_kernel(
    const unsigned short* __restrict__ hs3,
    const float* __restrict__ w3, const float* __restrict__ b3,
    float* __restrict__ out)   // [4][3][128][128]
{
    __shared__ float wl[768];
    int t = threadIdx.x;
    for (int i = t; i < 768; i += 256) wl[i] = w3[i];
    __syncthreads();
    int p = blockIdx.x * 64 + (t >> 2);   // global pixel 0..65535  (grid = 1024)
    int q = t & 3;                        // channel-quarter
    const unsigned short* src = hs3 + (size_t)p * 256 + q * 64;
    float a0 = 0.f, a1 = 0.f, a2 = 0.f;
    #pragma unroll
    for (int c8 = 0; c8 < 64; c8 += 8) {
        int4 pk = *(const int4*)(src + c8);
        #pragma unroll
        for (int qq = 0; qq < 4; ++qq) {
            unsigned uu = ((const unsigned*)&pk)[qq];
            float ve = bf2f((unsigned short)(uu & 0xffffu));
            float vo = bf2f((unsigned short)(uu >> 16));
            int c = q * 64 + c8 + qq * 2;
            a0 += ve * wl[c] + vo * wl[c + 1];
            a1 += ve * wl[256 + c] + vo * wl[256 + c + 1];
            a2 += ve * wl[512 + c] + vo * wl[512 + c + 1];
        }
    }
    a0 += __shfl_xor(a0, 1, 64); a0 += __shfl_xor(a0, 2, 64);
    a1 += __shfl_xor(a1, 1, 64); a1 += __shfl_xor(a1, 2, 64);
    a2 += __shfl_xor(a2, 1, 64); a2 += __shfl_xor(a2, 2, 64);
    int b = p >> 14, yx = p & 16383;
    if (q < 3) {
        float v = (q == 0) ? a0 : (q == 1) ? a1 : a2;
        out[((size_t)b * 3 + q) * 16384 + yx] = lrelu(v + b3[q]);
    }
}

extern "C" void kernel_launch(void* const* d_in, const int* in_sizes, int n_in,
                              void* d_out, int out_size, void* d_ws, size_t ws_size,
                              hipStream_t stream) {
    const float* x   = (const float*)d_in[0];
    const float* w   = (const float*)d_in[1];
    const float* w1  = (const float*)d_in[2];
    const float* b1  = (const float*)d_in[3];
    const float* a1w = (const float*)d_in[4];
    const float* a1b = (const float*)d_in[5];
    const float* w2  = (const float*)d_in[6];
    const float* b2  = (const float*)d_in[7];
    const float* a2w = (const float*)d_in[8];
    const float* a2b = (const float*)d_in[9];
    const float* w3  = (const float*)d_in[10];
    const float* b3  = (const float*)d_in[11];
    const float* a3w = (const float*)d_in[12];
    const float* a3b = (const float*)d_in[13];

    char* ws = (char*)d_ws;
    unsigned short* xu  = (unsigned short*)(ws);                 // 67108864 B [4][128][128][512] bf16
    unsigned short* hs3 = (unsigned short*)(ws);                 // aliases xu (xu dead after conv1)
    unsigned short* t1  = (unsigned short*)(ws + 67108864);      // 33554432 B [4][128][128][256] bf16
    unsigned short* wp1 = (unsigned short*)(ws + 100663296);     // 2359296 B
    unsigned short* wp2 = (unsigned short*)(ws + 103022592);     // 1179648 B
    float* s1 = (float*)(ws + 104202240);                        // 4*512
    float* s2 = (float*)(ws + 104210432);                        // 4*256
    float* s3 = (float*)(ws + 104214528);                        // 4*256
    float* d1 = (float*)(ws + 104218624);                        // 4*256
    float* d2 = (float*)(ws + 104222720);                        // 4*256

    float* h_out   = (float*)d_out;
    float* rgb_out = h_out + 16777216;

    style_kernel<<<1024, 256, 0, stream>>>(w, a1w, a1b, a2w, a2b, a3w, a3b, s1, s2, s3);
    demod_kernel<<<2048, 256, 0, stream>>>(w1, w2, s1, s2, d1, d2);
    pack_kernel<<<6912, 256, 0, stream>>>(w1, w2, wp1, wp2);
    upsample_kernel<<<512, 256, 0, stream>>>(x, s1, xu);
    conv3x3_kernel<512, false><<<1024, 256, 0, stream>>>(xu, wp1, d1, b1, s2, t1, nullptr);
    conv3x3_kernel<256, true><<<1024, 256, 0, stream>>>(t1, wp2, d2, b2, s3, hs3, h_out);
    rgb_kernel<<<1024, 256, 0, stream>>>(hs3, w3, b3, rgb_out);
}

// Round 4
// 381.004 us; speedup vs baseline: 1.2256x; 1.0281x over previous
//
#include <hip/hip_runtime.h>
#include <stdint.h>

typedef __attribute__((ext_vector_type(8))) short bhalf8;
typedef __attribute__((ext_vector_type(4))) float fx4;

__device__ __forceinline__ unsigned short f2bf(float f) {
    unsigned u = __builtin_bit_cast(unsigned, f);
    unsigned r = (u + 0x7fffu + ((u >> 16) & 1u)) >> 16;
    return (unsigned short)r;
}
__device__ __forceinline__ float bf2f(unsigned short h) {
    unsigned u = ((unsigned)h) << 16;
    return __builtin_bit_cast(float, u);
}
__device__ __forceinline__ float lrelu(float v) { return v > 0.f ? v : 0.2f * v; }

typedef __attribute__((address_space(1))) void as1_void;
typedef __attribute__((address_space(3))) void as3_void;
__device__ __forceinline__ void gl_lds16(const void* g, void* l) {
    __builtin_amdgcn_global_load_lds((as1_void*)(void*)g, (as3_void*)l, 16, 0, 0);
}

// ---------------- styles: s = w @ a^T + b  (one wave per output) ----------------
__global__ __launch_bounds__(256) void style_kernel(
    const float* __restrict__ w,
    const float* __restrict__ a1w, const float* __restrict__ a1b,
    const float* __restrict__ a2w, const float* __restrict__ a2b,
    const float* __restrict__ a3w, const float* __restrict__ a3b,
    float* __restrict__ s1, float* __restrict__ s2, float* __restrict__ s3)
{
    int gw = blockIdx.x * 4 + (threadIdx.x >> 6);   // 0..4095
    int lane = threadIdx.x & 63;
    int b = gw >> 10, r = gw & 1023;
    const float* arow; const float* abias; float* dst;
    if (r < 512)      { arow = a1w + (size_t)r * 512;        abias = a1b + r;       dst = s1 + b * 512 + r; }
    else if (r < 768) { int rr = r - 512; arow = a2w + (size_t)rr * 512; abias = a2b + rr; dst = s2 + b * 256 + rr; }
    else              { int rr = r - 768; arow = a3w + (size_t)rr * 512; abias = a3b + rr; dst = s3 + b * 256 + rr; }
    const float* wrow = w + b * 512;
    float acc = 0.f;
    #pragma unroll
    for (int j = 0; j < 8; ++j) {
        int c = lane + j * 64;
        acc += wrow[c] * arow[c];
    }
    #pragma unroll
    for (int off = 32; off; off >>= 1) acc += __shfl_down(acc, off, 64);
    if (lane == 0) *dst = acc + *abias;
}

// ---------------- demod: d[b,o] = rsqrt(sum_{i,tap}(w*s)^2 + eps) ----------------
__global__ __launch_bounds__(256) void demod_kernel(
    const float* __restrict__ w1, const float* __restrict__ w2,
    const float* __restrict__ s1, const float* __restrict__ s2,
    float* __restrict__ d1, float* __restrict__ d2)
{
    int blk = blockIdx.x;                 // 2048 blocks
    int conv = blk >> 10, b = (blk >> 8) & 3, o = blk & 255;
    int t = threadIdx.x;
    int cin = conv ? 256 : 512;
    const float* s = conv ? (s2 + b * 256) : (s1 + b * 512);
    const float* row = (conv ? w2 : w1) + (size_t)o * cin * 9;
    __shared__ float sv[512];
    for (int i = t; i < cin; i += 256) { float v = s[i]; sv[i] = v * v; }
    __syncthreads();
    float sum = 0.f;
    int n = cin * 9;
    for (int k = t; k < n; k += 256) {
        float v = row[k];
        sum += v * v * sv[k / 9];
    }
    #pragma unroll
    for (int off = 32; off; off >>= 1) sum += __shfl_down(sum, off, 64);
    __shared__ float red[4];
    if ((t & 63) == 0) red[t >> 6] = sum;
    __syncthreads();
    if (t == 0) {
        float tot = red[0] + red[1] + red[2] + red[3];
        (conv ? d2 : d1)[b * 256 + o] = rsqrtf(tot + 1e-8f);
    }
}

// ---------------- pack weights to bf16, fragment-linear layout ----------------
// layout: [mblk][dy][ic][dx][kh][m(128)][e(8)]
__global__ __launch_bounds__(256) void pack_kernel(
    const float* __restrict__ w1, const float* __restrict__ w2,
    unsigned short* __restrict__ wp1, unsigned short* __restrict__ wp2)
{
    int tid = blockIdx.x * 256 + threadIdx.x;
    const int N1 = 1179648, N2 = 589824;
    if (tid < N1) {
        int e = tid & 7, m = (tid >> 3) & 127, kh = (tid >> 10) & 3;
        int dx = (tid >> 12) % 3, ic = (tid / 12288) & 15;
        int dy = (tid / 196608) % 3, mblk = tid / 589824;
        int o = mblk * 128 + m, ci = ic * 32 + kh * 8 + e;
        wp1[tid] = f2bf(w1[((size_t)o * 512 + ci) * 9 + dy * 3 + dx]);
    } else if (tid < N1 + N2) {
        int t2 = tid - N1;
        int e = t2 & 7, m = (t2 >> 3) & 127, kh = (t2 >> 10) & 3;
        int dx = (t2 >> 12) % 3, ic = (t2 / 12288) & 7;
        int dy = (t2 / 98304) % 3, mblk = t2 / 294912;
        int o = mblk * 128 + m, ci = ic * 32 + kh * 8 + e;
        wp2[t2] = f2bf(w2[((size_t)o * 256 + ci) * 9 + dy * 3 + dx]);
    }
}

// ---------------- bilinear 2x upsample + s1 modulate -> bf16 channels-last ----------------
__global__ __launch_bounds__(256) void upsample_kernel(
    const float* __restrict__ x, const float* __restrict__ s1,
    unsigned short* __restrict__ xu)   // [4][128][128][512]
{
    __shared__ float L[2][64][65];
    int bid = blockIdx.x, t = threadIdx.x;
    int yo = bid & 127, b = bid >> 7;
    int k = yo >> 1;
    int sy0, sy1; float wy0, wy1;
    if ((yo & 1) == 0) { sy0 = k > 0 ? k - 1 : 0; sy1 = k; wy0 = 0.25f; wy1 = 0.75f; }
    else               { sy0 = k; sy1 = k < 63 ? k + 1 : 63; wy0 = 0.75f; wy1 = 0.25f; }
    for (int c0 = 0; c0 < 512; c0 += 64) {
        __syncthreads();
        #pragma unroll
        for (int j = 0; j < 32; ++j) {      // stage 2 rows x 64 c x 64 px
            int f = t + j * 256;
            int idx = f & 63, rowid = f >> 6;
            int cc = rowid & 63, which = rowid >> 6;
            int sy = which ? sy1 : sy0;
            L[which][cc][idx] = x[((size_t)(b * 512 + c0 + cc) * 64 + sy) * 64 + idx];
        }
        __syncthreads();
        #pragma unroll
        for (int j = 0; j < 16; ++j) {      // 128 x * 32 cpairs
            int it = t + j * 256;
            int cp = it & 31, xo = it >> 5;
            int kk = xo >> 1, sx0, sx1; float wx0, wx1;
            if ((xo & 1) == 0) { sx0 = kk > 0 ? kk - 1 : 0; sx1 = kk; wx0 = 0.25f; wx1 = 0.75f; }
            else               { sx0 = kk; sx1 = kk < 63 ? kk + 1 : 63; wx0 = 0.75f; wx1 = 0.25f; }
            int c = cp * 2;
            float A0 = wx0 * L[0][c][sx0] + wx1 * L[0][c][sx1];
            float B0 = wx0 * L[1][c][sx0] + wx1 * L[1][c][sx1];
            float A1 = wx0 * L[0][c + 1][sx0] + wx1 * L[0][c + 1][sx1];
            float B1 = wx0 * L[1][c + 1][sx0] + wx1 * L[1][c + 1][sx1];
            float v0 = (wy0 * A0 + wy1 * B0) * s1[b * 512 + c0 + c];
            float v1 = (wy0 * A1 + wy1 * B1) * s1[b * 512 + c0 + c + 1];
            unsigned pk = (unsigned)f2bf(v0) | ((unsigned)f2bf(v1) << 16);
            *(unsigned*)&xu[((size_t)(b * 128 + yo) * 128 + xo) * 512 + c0 + c] = pk;
        }
    }
}

// ---------------- 3x3 conv, implicit im2col, bf16 MFMA 16x16x32 ----------------
// Tile: 128 Cout x 256 px (2 output rows). 512 threads = 8 waves of 64x64.
// Per ic: stage 4 input rows once; per dy: stage A (24KB), compute 3 dx.
template<int CIN, bool IS_CONV2>
__global__ __launch_bounds__(512, 4) void conv3x3_kernel(
    const unsigned short* __restrict__ inp,
    const unsigned short* __restrict__ wpack,
    const float* __restrict__ dvec,
    const float* __restrict__ bias,
    const float* __restrict__ post,
    unsigned short* __restrict__ outmod,
    float* __restrict__ outf)
{
    constexpr int NIC = CIN / 32;
    __shared__ __attribute__((aligned(16))) short Alds[3 * 4096];   // [dx][kh][m128][e8] 24576 B
    __shared__ __attribute__((aligned(16))) short Blds[4][4160];    // 4 rows x [slot130][8x8 swz] 33280 B
    const int tid = threadIdx.x;
    const int lane = tid & 63;
    const int wvi = tid >> 6;         // 0..7
    const int bid = blockIdx.x;       // grid 512 = b(4) x mblk(2) x y2(64)
    const int y0 = (bid & 63) << 1;
    const int mblk = (bid >> 6) & 1;
    const int b = bid >> 7;
    const int wm = (wvi >> 2) * 64;
    const int row = (wvi >> 1) & 1;   // which of the 2 output rows
    const int wn = (wvi & 1) * 64;
    const int lhi = lane >> 4;
    const int llo = lane & 15;

    if (tid < 32) {   // zero column-halo pad slots 0 and 129 of each row buffer
        int buf = tid >> 3, slot = ((tid >> 2) & 1) ? 129 : 0, part = tid & 3;
        *(int4*)((char*)&Blds[buf][0] + slot * 64 + part * 16) = make_int4(0, 0, 0, 0);
    }

    fx4 acc[4][4];
    #pragma unroll
    for (int mt = 0; mt < 4; ++mt)
        #pragma unroll
        for (int nt = 0; nt < 4; ++nt) acc[mt][nt] = (fx4){0.f, 0.f, 0.f, 0.f};

    for (int ic = 0; ic < NIC; ++ic) {
        // stage 4 input rows (y0-1 .. y0+2), 8 KB each, once per ic
        {
            const int xg = tid >> 2, i8 = tid & 3;
            const int i8s = i8 ^ ((xg >> 1) & 3);
            #pragma unroll
            for (int rr = 0; rr < 4; ++rr) {
                const int yy = y0 - 1 + rr;
                char* dstB = (char*)&Blds[rr][0] + 64 + tid * 16;
                if ((unsigned)yy < 128u) {
                    gl_lds16(inp + ((size_t)(b * 128 + yy) * 128 + xg) * CIN + ic * 32 + i8s * 8, dstB);
                } else {
                    *(int4*)dstB = make_int4(0, 0, 0, 0);
                }
            }
        }
        // stage A for dy=0
        {
            const unsigned short* asrc = wpack + ((size_t)(mblk * 3 + 0) * NIC + ic) * 12288;
            #pragma unroll
            for (int j = 0; j < 3; ++j) {
                int g = tid + j * 512;
                gl_lds16(asrc + (size_t)g * 8, (char*)Alds + g * 16);
            }
        }
        __syncthreads();
        #pragma unroll
        for (int dy = 0; dy < 3; ++dy) {
            const short* Brow = &Blds[row + dy][0];
            #pragma unroll
            for (int dx = 0; dx < 3; ++dx) {
                bhalf8 af[4], bfr[4];
                #pragma unroll
                for (int mt = 0; mt < 4; ++mt)
                    af[mt] = *(const bhalf8*)&Alds[dx * 4096 + (lhi * 128 + wm + mt * 16 + llo) * 8];
                #pragma unroll
                for (int nt = 0; nt < 4; ++nt) {
                    int s = wn + nt * 16 + llo + dx;
                    int key = ((s - 1) >> 1) & 3;
                    bfr[nt] = *(const bhalf8*)&Brow[s * 32 + ((lhi ^ key) << 3)];
                }
                #pragma unroll
                for (int mt = 0; mt < 4; ++mt)
                    #pragma unroll
                    for (int nt = 0; nt < 4; ++nt)
                        acc[mt][nt] = __builtin_amdgcn_mfma_f32_16x16x32_bf16(
                            af[mt], bfr[nt], acc[mt][nt], 0, 0, 0);
            }
            __syncthreads();
            if (dy < 2) {
                const unsigned short* asrc = wpack + ((size_t)(mblk * 3 + dy + 1) * NIC + ic) * 12288;
                #pragma unroll
                for (int j = 0; j < 3; ++j) {
                    int g = tid + j * 512;
                    gl_lds16(asrc + (size_t)g * 8, (char*)Alds + g * 16);
                }
                __syncthreads();
            }
        }
    }

    // epilogue
    const int y = y0 + row;
    #pragma unroll
    for (int mt = 0; mt < 4; ++mt) {
        const int o0 = mblk * 128 + wm + mt * 16 + lhi * 4;
        const fx4 d4 = *(const fx4*)(dvec + b * 256 + o0);
        const fx4 bb4 = *(const fx4*)(bias + o0);
        const fx4 p4 = *(const fx4*)(post + b * 256 + o0);
        #pragma unroll
        for (int nt = 0; nt < 4; ++nt) {
            const int xo = wn + nt * 16 + llo;
            unsigned lo = 0, hi = 0;
            #pragma unroll
            for (int r = 0; r < 4; ++r) {
                float v = acc[mt][nt][r] * d4[r] + bb4[r];
                v = lrelu(v);
                if (IS_CONV2)
                    outf[(((size_t)b * 256 + o0 + r) * 128 + y) * 128 + xo] = v;
                unsigned short ub = f2bf(v * p4[r]);
                if (r < 2) lo |= (unsigned)ub << (16 * r);
                else       hi |= (unsigned)ub << (16 * (r - 2));
            }
            *(uint2*)&outmod[((size_t)(b * 128 + y) * 128 + xo) * 256 + o0] = make_uint2(lo, hi);
        }
    }
}

// ---------------- 1x1 to_rgb on h*s3 (bf16), coalesced: 4 lanes per pixel ----------------
__global__ __launch_bounds__(256) void rgb_kernel(
    const unsigned short* __restrict__ hs3,
    const float* __restrict__ w3, const float* __restrict__ b3,
    float* __restrict__ out)   // [4][3][128][128]
{
    __shared__ float wl[768];
    int t = threadIdx.x;
    for (int i = t; i < 768; i += 256) wl[i] = w3[i];
    __syncthreads();
    int p = blockIdx.x * 64 + (t >> 2);   // global pixel 0..65535  (grid = 1024)
    int q = t & 3;                        // channel-quarter
    const unsigned short* src = hs3 + (size_t)p * 256 + q * 64;
    float a0 = 0.f, a1 = 0.f, a2 = 0.f;
    #pragma unroll
    for (int c8 = 0; c8 < 64; c8 += 8) {
        int4 pk = *(const int4*)(src + c8);
        #pragma unroll
        for (int qq = 0; qq < 4; ++qq) {
            unsigned uu = ((const unsigned*)&pk)[qq];
            float ve = bf2f((unsigned short)(uu & 0xffffu));
            float vo = bf2f((unsigned short)(uu >> 16));
            int c = q * 64 + c8 + qq * 2;
            a0 += ve * wl[c] + vo * wl[c + 1];
            a1 += ve * wl[256 + c] + vo * wl[256 + c + 1];
            a2 += ve * wl[512 + c] + vo * wl[512 + c + 1];
        }
    }
    a0 += __shfl_xor(a0, 1, 64); a0 += __shfl_xor(a0, 2, 64);
    a1 += __shfl_xor(a1, 1, 64); a1 += __shfl_xor(a1, 2, 64);
    a2 += __shfl_xor(a2, 1, 64); a2 += __shfl_xor(a2, 2, 64);
    int b = p >> 14, yx = p & 16383;
    if (q < 3) {
        float v = (q == 0) ? a0 : (q == 1) ? a1 : a2;
        out[((size_t)b * 3 + q) * 16384 + yx] = lrelu(v + b3[q]);
    }
}

extern "C" void kernel_launch(void* const* d_in, const int* in_sizes, int n_in,
                              void* d_out, int out_size, void* d_ws, size_t ws_size,
                              hipStream_t stream) {
    const float* x   = (const float*)d_in[0];
    const float* w   = (const float*)d_in[1];
    const float* w1  = (const float*)d_in[2];
    const float* b1  = (const float*)d_in[3];
    const float* a1w = (const float*)d_in[4];
    const float* a1b = (const float*)d_in[5];
    const float* w2  = (const float*)d_in[6];
    const float* b2  = (const float*)d_in[7];
    const float* a2w = (const float*)d_in[8];
    const float* a2b = (const float*)d_in[9];
    const float* w3  = (const float*)d_in[10];
    const float* b3  = (const float*)d_in[11];
    const float* a3w = (const float*)d_in[12];
    const float* a3b = (const float*)d_in[13];

    char* ws = (char*)d_ws;
    unsigned short* xu  = (unsigned short*)(ws);                 // 67108864 B [4][128][128][512] bf16
    unsigned short* hs3 = (unsigned short*)(ws);                 // aliases xu (xu dead after conv1)
    unsigned short* t1  = (unsigned short*)(ws + 67108864);      // 33554432 B [4][128][128][256] bf16
    unsigned short* wp1 = (unsigned short*)(ws + 100663296);     // 2359296 B
    unsigned short* wp2 = (unsigned short*)(ws + 103022592);     // 1179648 B
    float* s1 = (float*)(ws + 104202240);                        // 4*512
    float* s2 = (float*)(ws + 104210432);                        // 4*256
    float* s3 = (float*)(ws + 104214528);                        // 4*256
    float* d1 = (float*)(ws + 104218624);                        // 4*256
    float* d2 = (float*)(ws + 104222720);                        // 4*256

    float* h_out   = (float*)d_out;
    float* rgb_out = h_out + 16777216;

    style_kernel<<<1024, 256, 0, stream>>>(w, a1w, a1b, a2w, a2b, a3w, a3b, s1, s2, s3);
    demod_kernel<<<2048, 256, 0, stream>>>(w1, w2, s1, s2, d1, d2);
    pack_kernel<<<6912, 256, 0, stream>>>(w1, w2, wp1, wp2);
    upsample_kernel<<<512, 256, 0, stream>>>(x, s1, xu);
    conv3x3_kernel<512, false><<<512, 512, 0, stream>>>(xu, wp1, d1, b1, s2, t1, nullptr);
    conv3x3_kernel<256, true><<<512, 512, 0, stream>>>(t1, wp2, d2, b2, s3, hs3, h_out);
    rgb_kernel<<<1024, 256, 0, stream>>>(hs3, w3, b3, rgb_out);
}